// Round 4
// baseline (511.493 us; speedup 1.0000x reference)
//
#include <hip/hip_runtime.h>
#include <hip/hip_bf16.h>

typedef __attribute__((ext_vector_type(8))) short short8;
typedef __attribute__((ext_vector_type(4))) float f32x4;

#define S_DIM 384
#define N_DIM 512
#define C_DIM 32
#define CZ_DIM 128
#define MROWS (S_DIM * C_DIM) /* 12288 */

__device__ __forceinline__ void async16(const void* g, void* l) {
  __builtin_amdgcn_global_load_lds(
      (const __attribute__((address_space(1))) void*)g,
      (__attribute__((address_space(3))) void*)l, 16, 0, 0);
}

// Kernel 1: LayerNorm + w_ab projection.
// Emits A[(s*32+c)*512 + n] = a(s,n,c)/512 (bf16), B[(s*32+d)*512 + n] = b(s,n,d) (bf16).
__global__ __launch_bounds__(256) void prep_kernel(
    const float* __restrict__ m_si, const float* __restrict__ ln_g,
    const float* __restrict__ ln_b, const float* __restrict__ w_ab,
    __hip_bfloat16* __restrict__ Abt, __hip_bfloat16* __restrict__ Bbt) {
  const int n = blockIdx.x * 256 + threadIdx.x;  // 0..511
  const int s = blockIdx.y;                      // 0..383
  const float* x = m_si + ((size_t)s * N_DIM + n) * C_DIM;

  float v[C_DIM];
#pragma unroll
  for (int i = 0; i < 8; ++i) {
    float4 t = ((const float4*)x)[i];
    v[4 * i + 0] = t.x; v[4 * i + 1] = t.y;
    v[4 * i + 2] = t.z; v[4 * i + 3] = t.w;
  }
  float sum = 0.f;
#pragma unroll
  for (int c = 0; c < C_DIM; ++c) sum += v[c];
  const float mu = sum * (1.f / 32.f);
  float sq = 0.f;
#pragma unroll
  for (int c = 0; c < C_DIM; ++c) { float d = v[c] - mu; sq += d * d; }
  const float rstd = rsqrtf(sq * (1.f / 32.f) + 1e-5f);

  float mn[C_DIM];
#pragma unroll
  for (int c = 0; c < C_DIM; ++c)
    mn[c] = (v[c] - mu) * rstd * ln_g[c] + ln_b[c];

#pragma unroll 4
  for (int d = 0; d < 32; ++d) {
    float aA = 0.f, aB = 0.f;
#pragma unroll
    for (int c = 0; c < C_DIM; ++c) {
      aA += mn[c] * w_ab[d * C_DIM + c];          // uniform idx -> s_loads
      aB += mn[c] * w_ab[(d + 32) * C_DIM + c];
    }
    Abt[((size_t)(s * 32 + d)) * N_DIM + n] = __float2bfloat16(aA * (1.f / 512.f));
    Bbt[((size_t)(s * 32 + d)) * N_DIM + n] = __float2bfloat16(aB);
  }
}

// Kernel 2: w_final fp32 -> bf16 (128 x 1024)
__global__ __launch_bounds__(256) void conv_wf(const float* __restrict__ w_final,
                                               __hip_bfloat16* __restrict__ Wf) {
  const int i = blockIdx.x * 256 + threadIdx.x;
  Wf[i] = __float2bfloat16(w_final[i]);
}

// Kernel 3: fused outer-product GEMM (256x256 tile, K=512) + w_final epilogue.
// 512 threads = 8 waves (2 M x 4 N); per-wave output 128x64 (8x4 16x16 frags).
// DEEP PIPELINE (T3+T4): 4-slot circular LDS (BK=32, 32KB/slot), depth-3 prefetch,
// counted s_waitcnt vmcnt(8) per K-tile, RAW s_barrier (never __syncthreads ->
// never a vmcnt(0) drain in steady state). One barrier per K-tile.
// Safety invariants:
//  - stage at iter kt writes slot (kt+3)&3 = (kt-1)&3, whose readers (compute kt-1)
//    all finished before this iter's s_barrier.
//  - compute(kt) reads slot kt&3, only overwritten by iter kt+1's stage, which is
//    behind iter kt+1's barrier; sched_barrier(0) fences stop cross-barrier motion.
//  - vmcnt(8) leaves tiles kt+1,kt+2 (8 loads) in flight; tail 8/4/0 at kt=13/14/15.
__global__ __launch_bounds__(512, 2) void fused_opm(
    const __hip_bfloat16* __restrict__ Abt, const __hip_bfloat16* __restrict__ Bbt,
    const __hip_bfloat16* __restrict__ Wf, const float* __restrict__ b_final,
    float* __restrict__ out) {
  // 4 slots x (A[256][32] + B[256][32]) bf16 = 4 x 32KB = 128KB.
  // Epilogue reuses all 128KB as Oc[64 cells][1024] bf16 (slot-swizzled).
  __shared__ __align__(16) char smem[131072];

  const int tid = threadIdx.x;
  const int wave = tid >> 6;
  const int lane = tid & 63;
  const int fr = lane & 15;              // MFMA row/col-within-tile
  const int fq = lane >> 4;              // MFMA quad
  const int fqs = fq ^ ((fr >> 1) & 3);  // swizzled physical k-slot (R2 scheme)
  const int wr = wave >> 2;              // 0..1  (M)
  const int wc = wave & 3;               // 0..3  (N)
  const int bi = blockIdx.y, bj = blockIdx.x;

  const size_t m0 = (size_t)bi * 256;
  const size_t n0 = (size_t)bj * 256;

  // Staging: per K-tile, A = 16KB (2 issues of 512 x 16B), B likewise.
  // Linear LDS dest; k-chunk swizzle realized by pre-swizzled GLOBAL source.
  const int srow = tid >> 2;                             // 0..127 (+128 on 2nd issue)
  const int sk = (((tid & 3) ^ ((tid >> 3) & 3)) * 8);   // pre-swizzled k offset
  const __hip_bfloat16* gA = Abt + (m0 + srow) * N_DIM + sk;
  const __hip_bfloat16* gB = Bbt + (n0 + srow) * N_DIM + sk;
  const int ldst = tid * 16;

  const f32x4 fzero = {0.f, 0.f, 0.f, 0.f};
  f32x4 acc[8][4];
#pragma unroll
  for (int i = 0; i < 8; ++i)
#pragma unroll
    for (int j = 0; j < 4; ++j) acc[i][j] = fzero;

  auto stage = [&](int kt, int slot) {
    char* base = smem + slot * 32768;
    const int k0 = kt * 32;
    async16(gA + k0, base + ldst);                                   // A rows 0..127
    async16(gA + (size_t)128 * N_DIM + k0, base + 8192 + ldst);      // A rows 128..255
    async16(gB + k0, base + 16384 + ldst);                           // B rows 0..127
    async16(gB + (size_t)128 * N_DIM + k0, base + 24576 + ldst);     // B rows 128..255
  };

  auto compute = [&](int slot) {
    const __hip_bfloat16* As = (const __hip_bfloat16*)(smem + slot * 32768);
    const __hip_bfloat16* Bs = (const __hip_bfloat16*)(smem + slot * 32768 + 16384);
    short8 bf_[4];
#pragma unroll
    for (int nt = 0; nt < 4; ++nt)
      bf_[nt] = *(const short8*)(Bs + (wc * 64 + nt * 16 + fr) * 32 + fqs * 8);
    __builtin_amdgcn_s_setprio(1);
#pragma unroll
    for (int mt = 0; mt < 8; ++mt) {
      const short8 a = *(const short8*)(As + (wr * 128 + mt * 16 + fr) * 32 + fqs * 8);
#pragma unroll
      for (int nt = 0; nt < 4; ++nt)
        acc[mt][nt] = __builtin_amdgcn_mfma_f32_16x16x32_bf16(a, bf_[nt],
                                                              acc[mt][nt], 0, 0, 0);
    }
    __builtin_amdgcn_s_setprio(0);
  };

  // Prologue: 3 K-tiles in flight (12 loads outstanding).
  stage(0, 0);
  stage(1, 1);
  stage(2, 2);

#pragma unroll
  for (int kt = 0; kt < 14; ++kt) {
    asm volatile("s_waitcnt vmcnt(8)" ::: "memory");  // tile kt landed (mine)
    __builtin_amdgcn_sched_barrier(0);
    __builtin_amdgcn_s_barrier();                     // everyone's tile kt landed;
    __builtin_amdgcn_sched_barrier(0);                // slot (kt+3)&3 readers done
    if (kt + 3 < 16) stage(kt + 3, (kt + 3) & 3);
    compute(kt & 3);
  }
  asm volatile("s_waitcnt vmcnt(4)" ::: "memory");    // tile 14 landed
  __builtin_amdgcn_sched_barrier(0);
  __builtin_amdgcn_s_barrier();
  __builtin_amdgcn_sched_barrier(0);
  compute(2);
  asm volatile("s_waitcnt vmcnt(0)" ::: "memory");    // tile 15 landed
  __builtin_amdgcn_sched_barrier(0);
  __builtin_amdgcn_s_barrier();
  __builtin_amdgcn_sched_barrier(0);
  compute(3);

  __syncthreads();  // all waves done with staging LDS; safe to repurpose as Oc

  // ---- Epilogue phase 1: o-tile (fp32 acc) -> Oc LDS bf16, slot-swizzled ----
  // Logical [cell][kk], cell = i_loc*8 + j_loc (0..63), kk = c*32+d (0..1023).
  // Physical: cell*1024 + (((kk>>3) ^ (cell&7))<<3 | (kk&7)).
  __hip_bfloat16* Oc = (__hip_bfloat16*)smem;  // [64][1024]
#pragma unroll
  for (int mt = 0; mt < 8; ++mt) {
#pragma unroll
    for (int nt = 0; nt < 4; ++nt) {
      const int orow_b = wr * 128 + mt * 16 + fq * 4;
      const int ocol = wc * 64 + nt * 16 + fr;  // C/D map: col=lane&15
#pragma unroll
      for (int r = 0; r < 4; ++r) {             // row=(lane>>4)*4+reg
        const int orow = orow_b + r;
        const int cell = ((orow >> 5) << 3) + (ocol >> 5);  // i_loc*8 + j_loc
        const int kk = ((orow & 31) << 5) + (ocol & 31);    // c*32+d
        const int sw = ((((kk >> 3) ^ (cell & 7)) << 3) | (kk & 7));
        Oc[cell * 1024 + sw] = __float2bfloat16(acc[mt][nt][r]);
      }
    }
  }
  __syncthreads();

  // ---- Epilogue phase 2: Z[64 cells][128] = Oc[64][1024] @ Wf[128][1024]^T ----
  // 8 waves: wave w -> cell-tile mt2 = w>>1 (16 cells), z-col group ng = w&1 (64 cols
  // as 4 n-tiles). K-loop 32 steps of 32.
  f32x4 zacc[4] = {fzero, fzero, fzero, fzero};
  const int mt2 = wave >> 1;
  const int ng = wave & 1;
  const int ocell = mt2 * 16 + fr;  // (cell&7) == fr&7 since 16*mt2 % 8 == 0
  const int xr = fr & 7;
#pragma unroll 4
  for (int kk = 0; kk < 32; ++kk) {
    const short8 oa =
        *(const short8*)(Oc + ocell * 1024 + (((kk * 4 + fq) ^ xr) << 3));
#pragma unroll
    for (int nt2 = 0; nt2 < 4; ++nt2) {
      const short8 wb = *(const short8*)(
          Wf + (size_t)(ng * 64 + nt2 * 16 + fr) * 1024 + kk * 32 + fq * 8);
      zacc[nt2] = __builtin_amdgcn_mfma_f32_16x16x32_bf16(oa, wb, zacc[nt2], 0, 0, 0);
    }
  }

  // ---- Epilogue phase 3: z-write (+ b_final) ----
  const int i0 = bi * 8, j0 = bj * 8;
#pragma unroll
  for (int nt2 = 0; nt2 < 4; ++nt2) {
    const int zcol = ng * 64 + nt2 * 16 + fr;
    const float bz = b_final[zcol];
#pragma unroll
    for (int r = 0; r < 4; ++r) {
      const int cell = mt2 * 16 + fq * 4 + r;  // D row = cell index
      const int li = cell >> 3, lj = cell & 7;
      out[((size_t)(i0 + li) * S_DIM + (j0 + lj)) * CZ_DIM + zcol] = zacc[nt2][r] + bz;
    }
  }
}

extern "C" void kernel_launch(void* const* d_in, const int* in_sizes, int n_in,
                              void* d_out, int out_size, void* d_ws, size_t ws_size,
                              hipStream_t stream) {
  const float* m_si = (const float*)d_in[0];
  const float* ln_g = (const float*)d_in[1];
  const float* ln_b = (const float*)d_in[2];
  const float* w_ab = (const float*)d_in[3];
  const float* w_final = (const float*)d_in[4];
  const float* b_final = (const float*)d_in[5];
  float* out = (float*)d_out;

  char* ws = (char*)d_ws;
  __hip_bfloat16* Abt = (__hip_bfloat16*)ws;                                // 12.58 MB
  __hip_bfloat16* Bbt = (__hip_bfloat16*)(ws + (size_t)MROWS * N_DIM * 2);  // 12.58 MB
  __hip_bfloat16* Wf = (__hip_bfloat16*)(ws + (size_t)MROWS * N_DIM * 4);   // 256 KB

  prep_kernel<<<dim3(2, S_DIM), 256, 0, stream>>>(m_si, ln_g, ln_b, w_ab, Abt, Bbt);
  conv_wf<<<dim3((CZ_DIM * 1024) / 256), 256, 0, stream>>>(w_final, Wf);
  fused_opm<<<dim3(48, 48), 512, 0, stream>>>(Abt, Bbt, Wf, b_final, out);
}